// Round 9
// baseline (459.563 us; speedup 1.0000x reference)
//
#include <hip/hip_runtime.h>

// RVQ: z [16,64,4096] f32, codebooks [8,1024,64] f32 -> zq + 8 losses + 8 perplexities
#define S      8
#define K      1024
#define D      64
#define NVEC   65536
#define NBLK   512       // 4-wave blocks, 128 vectors each (32/wave, dual row-set)
#define NW     2048      // loss partials (one per wave)
#define NELEM  4194304.0f
#define EPSQ   1e-10f
#define DELTA  0.005f    // exact-rescan margin >> split-bf16 score error (~2e-3 worst)

typedef __attribute__((ext_vector_type(8))) short  short8;   // 8 bf16
typedef __attribute__((ext_vector_type(4))) float  float4v;  // MFMA acc

static __device__ inline unsigned short f2bf(float f) {
    unsigned int u = __float_as_uint(f);
    u = (u + 0x7FFFu + ((u >> 16) & 1u)) >> 16;
    return (unsigned short)u;
}
static __device__ inline float bf2f(unsigned short h) {
    return __uint_as_float(((unsigned int)h) << 16);
}

// async global->LDS, 16 B per lane. LDS dest is WAVE-UNIFORM base (HW adds
// lane*16); global src is per-lane.
static __device__ inline void gll16(const void* g, void* l) {
    __builtin_amdgcn_global_load_lds(
        (const __attribute__((address_space(1))) unsigned int*)g,
        (__attribute__((address_space(3))) unsigned int*)l,
        16, 0, 0);
}

// ---------------------------------------------------------------------------
// Prep: (a) c2 + zero cnt; (b) interleave codebook into B-fragment streaming
// records, PRE-SCALED BY -2 so the MFMA accumulates -2*dot directly and the
// accumulator is seeded with c2 (score = acc, no per-score fmaf).
// Record = 4KB per (stage, 16-cw tile): segments at byte 0/1024/2048/3072
// ([h0h][h1h][h0l][h1l]), each segment 64 lanes x 16B.
// ---------------------------------------------------------------------------
__global__ void rvq_prep(const float* __restrict__ cb,
                         unsigned short* __restrict__ cbi,
                         float* __restrict__ c2, unsigned* __restrict__ cnt) {
    int i = blockIdx.x * blockDim.x + threadIdx.x;   // 0..32767
    if (i < S * K) {   // c2 + cnt zero
        const float* row = cb + (size_t)i * D;
        float a0 = 0.f, a1 = 0.f, a2 = 0.f, a3 = 0.f;
#pragma unroll
        for (int d = 0; d < D; d += 4) {
            a0 = fmaf(row[d+0], row[d+0], a0);
            a1 = fmaf(row[d+1], row[d+1], a1);
            a2 = fmaf(row[d+2], row[d+2], a2);
            a3 = fmaf(row[d+3], row[d+3], a3);
        }
        c2[i] = (a0 + a1) + (a2 + a3);
        cnt[i] = 0u;
    }
    // interleave: i = s*4096 + tau*64 + l
    int s  = i >> 12;
    int tau = (i >> 6) & 63;
    int l  = i & 63;
    int m  = l & 15, qq = l >> 4;
    const float* row = cb + (size_t)(s * K + tau * 16 + m) * D;
    short8 h0h, h0l, h1h, h1l;
#pragma unroll
    for (int e = 0; e < 8; ++e) {
        float x = -2.0f * row[qq * 8 + e];
        unsigned short h = f2bf(x);
        h0h[e] = (short)h; h0l[e] = (short)f2bf(x - bf2f(h));
        float y = -2.0f * row[32 + qq * 8 + e];
        unsigned short g = f2bf(y);
        h1h[e] = (short)g; h1l[e] = (short)f2bf(y - bf2f(g));
    }
    unsigned short* rec = cbi + (size_t)(s * 64 + tau) * 2048 + l * 8;
    *(short8*)(rec +    0) = h0h;
    *(short8*)(rec +  512) = h1h;
    *(short8*)(rec + 1024) = h0l;
    *(short8*)(rec + 1536) = h1l;
}

// ---------------------------------------------------------------------------
// Main (R9 = R8 architecture, crash surface removed). R8 crashed (SIGABRT,
// no counters); suspects all removed here: static LDS cut 68KB -> exactly
// 64KB (2x32KB aligned buffers; c2 read from global, L1-hot 4KB, as in
// R0-R7), and all raw s_barrier/inline-asm replaced with __syncthreads()
// (this schedule drains staging before every barrier anyway, so semantics
// are identical and compiler-reordering hazards are gone).
//
// Architecture (R7 post-mortem theory, still untested): the binder is every
// wave independently streaming 2MB/stage from L2 (~250cyc/tile) with ~2
// effective waves/SIMD. Here: 512 blocks x 4 waves x 32 vec (dual 16-row
// sets -> 12 MFMA per 16-cw tile, LDS reads amortized 2x). Each 4KB tile
// staged ONCE per block via global_load_lds; 8-tile chunks, ping-pong 32KB
// buffers, 2-phase: STAGE(next) -> compute 8 tiles -> __syncthreads.
// 9 barriers/stage with 96 MFMA between (R5 failed with 256 barriers/stage,
// 12 MFMA between).
//
// launch_bounds EMPIRICAL RULE (R0-R4): VGPR cap = 256/arg2 on this
// toolchain. arg2 MUST stay 2 (cap 128; dual-set core fit 124 in R2).
// ---------------------------------------------------------------------------
__global__ __launch_bounds__(256, 2)
void rvq_main(const float* __restrict__ z, const float* __restrict__ cbf,
              const unsigned short* __restrict__ cbi,
              const float* __restrict__ c2, float* __restrict__ zq,
              float* __restrict__ lossp, unsigned* __restrict__ cnt) {
    const int tid  = threadIdx.x;
    const int lane = tid & 63;
    const int w    = tid >> 6;              // wave 0..3
    const int m    = lane & 15;
    const int q    = lane >> 4;
    const int bid  = blockIdx.x;
    const int vbase = bid * 128 + w * 32;   // this wave's 32 vectors
    const int b    = vbase >> 12;
    const int ta   = (vbase & 4095) + m;    // set-a t
    const int tb   = ta + 16;               // set-b t
    const size_t zrow = ((size_t)(b * 64)) << 12;
    const int gwid = bid * 4 + w;           // global wave id 0..2047

    __shared__ __align__(16) char bufA[32768];
    __shared__ __align__(16) char bufB[32768];

    float ra0[8], ra1[8], rb0[8], rb1[8];
#pragma unroll
    for (int i = 0; i < 8; ++i) {
        ra0[i] = z[zrow + ((size_t)(q*8+i)    << 12) + ta];
        ra1[i] = z[zrow + ((size_t)(32+q*8+i) << 12) + ta];
        rb0[i] = z[zrow + ((size_t)(q*8+i)    << 12) + tb];
        rb1[i] = z[zrow + ((size_t)(32+q*8+i) << 12) + tb];
    }

// stage chunk c (8 tiles, 32KB); this wave stages bytes [w*8KB, w*8KB+8KB)
#define STAGE(c, dst) {                                                       \
        const char* sgp = recs + (size_t)(c) * 32768 + w * 8192 + lane * 16;  \
        char*       sdp = (dst) + w * 8192;                                   \
        _Pragma("unroll")                                                     \
        for (int i2 = 0; i2 < 8; ++i2)                                        \
            gll16(sgp + i2 * 1024, sdp + i2 * 1024);                          \
    }

#define MF(A,B,C) __builtin_amdgcn_mfma_f32_16x16x32_bf16(A,B,C,0,0,0)

// compute one 16-cw tile (ti within chunk) for both row-sets from LDS
#define COMPD(ti) {                                                           \
        const short8 bh0 = *(const short8*)(pb + (ti)*4096);                  \
        const short8 bh1 = *(const short8*)(pb + (ti)*4096 + 1024);           \
        const short8 bl0 = *(const short8*)(pb + (ti)*4096 + 2048);           \
        const short8 bl1 = *(const short8*)(pb + (ti)*4096 + 3072);           \
        const float c2v = c2s[cb16 + (ti)*16];                                \
        float4v aa = {c2v, c2v, c2v, c2v}, ab = {c2v, c2v, c2v, c2v};         \
        __builtin_amdgcn_s_setprio(1);                                        \
        aa = MF(xa0h, bh0, aa); ab = MF(xb0h, bh0, ab);                       \
        aa = MF(xa0l, bh0, aa); ab = MF(xb0l, bh0, ab);                       \
        aa = MF(xa0h, bl0, aa); ab = MF(xb0h, bl0, ab);                       \
        aa = MF(xa1h, bh1, aa); ab = MF(xb1h, bh1, ab);                       \
        aa = MF(xa1l, bh1, aa); ab = MF(xb1l, bh1, ab);                       \
        aa = MF(xa1h, bl1, aa); ab = MF(xb1h, bl1, ab);                       \
        __builtin_amdgcn_s_setprio(0);                                        \
        const int ncol = cb16 + (ti) * 16;                                    \
        _Pragma("unroll")                                                     \
        for (int j = 0; j < 4; ++j) {                                         \
            float sa = aa[j];                                                 \
            b2a[j] = __builtin_amdgcn_fmed3f(sa, b1a[j], b2a[j]);             \
            k1a[j] = (sa < b1a[j]) ? ncol : k1a[j];                           \
            b1a[j] = fminf(sa, b1a[j]);                                       \
            float sb = ab[j];                                                 \
            b2b[j] = __builtin_amdgcn_fmed3f(sb, b1b[j], b2b[j]);             \
            k1b[j] = (sb < b1b[j]) ? ncol : k1b[j];                           \
            b1b[j] = fminf(sb, b1b[j]);                                       \
        }                                                                     \
    }

#pragma unroll 1
    for (int s = 0; s < S; ++s) {
        // split residuals to bf16 hi/lo A-fragments
        short8 xa0h, xa0l, xa1h, xa1l, xb0h, xb0l, xb1h, xb1l;
#pragma unroll
        for (int i = 0; i < 8; ++i) {
            unsigned short h;
            h = f2bf(ra0[i]); xa0h[i] = (short)h; xa0l[i] = (short)f2bf(ra0[i] - bf2f(h));
            h = f2bf(ra1[i]); xa1h[i] = (short)h; xa1l[i] = (short)f2bf(ra1[i] - bf2f(h));
            h = f2bf(rb0[i]); xb0h[i] = (short)h; xb0l[i] = (short)f2bf(rb0[i] - bf2f(h));
            h = f2bf(rb1[i]); xb1h[i] = (short)h; xb1l[i] = (short)f2bf(rb1[i] - bf2f(h));
        }

        float b1a[4], b2a[4], b1b[4], b2b[4];
        int   k1a[4], k1b[4];
#pragma unroll
        for (int j = 0; j < 4; ++j) {
            b1a[j] = 3.4e38f; b2a[j] = 3.4e38f; k1a[j] = 0;
            b1b[j] = 3.4e38f; b2b[j] = 3.4e38f; k1b[j] = 0;
        }

        const char*  recs = (const char*)cbi + (size_t)s * 262144;
        const float* c2s  = c2 + s * K;

        // ---- prologue: stage chunk 0 ----
        STAGE(0, bufA)
        __syncthreads();

        // ---- 8 chunks x 8 tiles, 2-phase: stage(next) || compute(cur) ----
#pragma unroll 1
        for (int ch = 0; ch < 8; ++ch) {
            char* cur = (ch & 1) ? bufB : bufA;
            char* nxt = (ch & 1) ? bufA : bufB;
            if (ch < 7) STAGE(ch + 1, nxt)
            const char* pb  = cur + lane * 16;
            const int  cb16 = ch * 128 + m;
            COMPD(0) COMPD(1) COMPD(2) COMPD(3)
            COMPD(4) COMPD(5) COMPD(6) COMPD(7)
            __syncthreads();   // drains vmcnt (stage of next chunk) + barrier
        }

        // ---- reduce across the 16 col-lanes (k-tie: lowest k) ----
#pragma unroll
        for (int off = 1; off < 16; off <<= 1) {
#pragma unroll
            for (int j = 0; j < 4; ++j) {
                float o1 = __shfl_xor(b1a[j], off); int ok = __shfl_xor(k1a[j], off);
                float o2 = __shfl_xor(b2a[j], off);
                float n2 = fminf(fminf(b2a[j], o2), fmaxf(b1a[j], o1));
                bool tk = (o1 < b1a[j]) || (o1 == b1a[j] && ok < k1a[j]);
                k1a[j] = tk ? ok : k1a[j]; b1a[j] = fminf(b1a[j], o1); b2a[j] = n2;
                o1 = __shfl_xor(b1b[j], off); ok = __shfl_xor(k1b[j], off);
                o2 = __shfl_xor(b2b[j], off);
                n2 = fminf(fminf(b2b[j], o2), fmaxf(b1b[j], o1));
                tk = (o1 < b1b[j]) || (o1 == b1b[j] && ok < k1b[j]);
                k1b[j] = tk ? ok : k1b[j]; b1b[j] = fminf(b1b[j], o1); b2b[j] = n2;
            }
        }

        // ---- δ-rescue: exact fp32 rescan of ambiguous rows (rare) ----
        const float* cr0 = cbf + (size_t)s * 65536;
#define RESCUE(b1X, b2X, k1X, R0, R1)                                         \
        for (int j = 0; j < 4; ++j) {                                         \
            unsigned long long mask = __ballot(b2X[j] - b1X[j] < DELTA);      \
            while (mask) {                                                    \
                int lq = (int)(__builtin_ctzll(mask)) >> 4;                   \
                mask &= ~(0xFFFFULL << (lq * 16));                            \
                int mrow = lq * 4 + j;                                        \
                float bd = 3.4e38f; int bk = 0;                               \
                for (int cc = 0; cc < 16; ++cc) {                             \
                    int n = cc * 64 + lane;                                   \
                    const float* crow = cr0 + (size_t)n * 64;                 \
                    float dot = 0.f;                                          \
                    for (int p2 = 0; p2 < 4; ++p2) {                          \
                        for (int i = 0; i < 8; ++i)                           \
                            dot = fmaf(__shfl(R0[i], mrow + 16*p2), crow[p2*8+i], dot); \
                        for (int i = 0; i < 8; ++i)                           \
                            dot = fmaf(__shfl(R1[i], mrow + 16*p2), crow[32+p2*8+i], dot); \
                    }                                                         \
                    float sc = c2s[n] - 2.f * dot;                            \
                    if (sc < bd) { bd = sc; bk = n; }                         \
                }                                                             \
                for (int off = 1; off < 64; off <<= 1) {                      \
                    float ob = __shfl_xor(bd, off); int ok = __shfl_xor(bk, off); \
                    bool tk = (ob < bd) || (ob == bd && ok < bk);             \
                    bk = tk ? ok : bk; bd = fminf(bd, ob);                    \
                }                                                             \
                if (q == lq) k1X[j] = bk;                                     \
            }                                                                 \
        }
        RESCUE(b1a, b2a, k1a, ra0, ra1)
        RESCUE(b1b, b2b, k1b, rb0, rb1)
#undef RESCUE

        // ---- transpose winners to per-lane rows (row = m), convergent ----
        int mm = m & 3, src = (m >> 2) * 16;
        int wa0 = __shfl(k1a[0], src), wa1 = __shfl(k1a[1], src);
        int wa2 = __shfl(k1a[2], src), wa3 = __shfl(k1a[3], src);
        int bka = (mm == 0) ? wa0 : (mm == 1) ? wa1 : (mm == 2) ? wa2 : wa3;
        int wb0 = __shfl(k1b[0], src), wb1 = __shfl(k1b[1], src);
        int wb2 = __shfl(k1b[2], src), wb3 = __shfl(k1b[3], src);
        int bkb = (mm == 0) ? wb0 : (mm == 1) ? wb1 : (mm == 2) ? wb2 : wb3;

        // ---- fp32 residual update ----
        const float* qa = cbf + (size_t)s * 65536 + (size_t)bka * 64;
        const float* qb = cbf + (size_t)s * 65536 + (size_t)bkb * 64;
#pragma unroll
        for (int i = 0; i < 8; ++i) {
            ra0[i] -= qa[q*8+i];  ra1[i] -= qa[32+q*8+i];
            rb0[i] -= qb[q*8+i];  rb1[i] -= qb[32+q*8+i];
        }

        // ---- loss: per-wave partial (distinct vectors per wave) ----
        float ls = 0.f;
#pragma unroll
        for (int i = 0; i < 8; ++i) {
            ls = fmaf(ra0[i], ra0[i], ls); ls = fmaf(ra1[i], ra1[i], ls);
            ls = fmaf(rb0[i], rb0[i], ls); ls = fmaf(rb1[i], rb1[i], ls);
        }
#pragma unroll
        for (int off = 1; off < 64; off <<= 1) ls += __shfl_xor(ls, off);
        if (lane == 0) lossp[s * NW + gwid] = ls;

        // ---- histogram: per-vector winners (dup across q) ----
        if (q == 0) {
            atomicAdd(&cnt[s * K + bka], 1u);   // vector vbase+m
            atomicAdd(&cnt[s * K + bkb], 1u);   // vector vbase+16+m
        }
    }
#undef STAGE
#undef COMPD
#undef MF

    // ---- epilogue: zq = z - r_final ----
#pragma unroll
    for (int i = 0; i < 8; ++i) {
        size_t a0 = zrow + ((size_t)(q*8+i)    << 12) + ta;
        size_t a1 = zrow + ((size_t)(32+q*8+i) << 12) + ta;
        zq[a0] = z[a0] - ra0[i];
        zq[a1] = z[a1] - ra1[i];
        size_t a2 = zrow + ((size_t)(q*8+i)    << 12) + tb;
        size_t a3 = zrow + ((size_t)(32+q*8+i) << 12) + tb;
        zq[a2] = z[a2] - rb0[i];
        zq[a3] = z[a3] - rb1[i];
    }
}

// ---------------------------------------------------------------------------
// Finalize: losses (mean of summed wave partials) + perplexities
// ---------------------------------------------------------------------------
__global__ void rvq_finalize(const float* __restrict__ lossp,
                             const unsigned* __restrict__ cnt,
                             float* __restrict__ out_loss,
                             float* __restrict__ out_perp) {
    const int s   = blockIdx.x;
    const int tid = threadIdx.x;
    float ent = 0.f, lsum = 0.f;
    for (int i = tid; i < K; i += 256) {
        float p = (float)cnt[s * K + i] * (1.0f / 65536.0f);
        ent += p * logf(p + EPSQ);
    }
    for (int i = tid; i < NW; i += 256) lsum += lossp[s * NW + i];
    __shared__ float redE[4], redL[4];
#pragma unroll
    for (int off = 32; off > 0; off >>= 1) {
        ent  += __shfl_down(ent, off);
        lsum += __shfl_down(lsum, off);
    }
    if ((tid & 63) == 0) { redE[tid >> 6] = ent; redL[tid >> 6] = lsum; }
    __syncthreads();
    if (tid == 0) {
        float te = redE[0] + redE[1] + redE[2] + redE[3];
        float tl = redL[0] + redL[1] + redL[2] + redL[3];
        out_perp[s] = expf(-te);
        out_loss[s] = tl * (1.0f / NELEM);
    }
}

// ---------------------------------------------------------------------------
extern "C" void kernel_launch(void* const* d_in, const int* in_sizes, int n_in,
                              void* d_out, int out_size, void* d_ws, size_t ws_size,
                              hipStream_t stream) {
    const float* z  = (const float*)d_in[0];
    const float* cb = (const float*)d_in[1];

    float* zq       = (float*)d_out;
    float* out_loss = zq + 4194304;
    float* out_perp = out_loss + 8;

    // ws: cbi 2 MB | c2 32 KB | cnt 32 KB | lossp 64 KB
    char* ws = (char*)d_ws;
    unsigned short* cbi = (unsigned short*)(ws);
    float*    c2    = (float*)(ws + 2097152);
    unsigned* cnt   = (unsigned*)(ws + 2129920);
    float*    lossp = (float*)(ws + 2162688);

    hipLaunchKernelGGL(rvq_prep,     dim3(128),  dim3(256), 0, stream, cb, cbi, c2, cnt);
    hipLaunchKernelGGL(rvq_main,     dim3(NBLK), dim3(256), 0, stream, z, cb, cbi, c2, zq, lossp, cnt);
    hipLaunchKernelGGL(rvq_finalize, dim3(S),    dim3(256), 0, stream, lossp, cnt, out_loss, out_perp);
}

// Round 10
// 364.955 us; speedup vs baseline: 1.2592x; 1.2592x over previous
//
#include <hip/hip_runtime.h>

// RVQ: z [16,64,4096] f32, codebooks [8,1024,64] f32 -> zq + 8 losses + 8 perplexities
#define S      8
#define K      1024
#define D      64
#define NVEC   65536
#define NW     2048      // single-wave blocks, 32 vectors each (dual row-set)
#define NELEM  4194304.0f
#define EPSQ   1e-10f
#define DELTA  0.005f    // exact-rescan margin >> split-bf16 score error (~2e-3 worst)

typedef __attribute__((ext_vector_type(8))) short  short8;   // 8 bf16
typedef __attribute__((ext_vector_type(4))) float  float4v;  // MFMA acc

static __device__ inline unsigned short f2bf(float f) {
    unsigned int u = __float_as_uint(f);
    u = (u + 0x7FFFu + ((u >> 16) & 1u)) >> 16;
    return (unsigned short)u;
}
static __device__ inline float bf2f(unsigned short h) {
    return __uint_as_float(((unsigned int)h) << 16);
}

// ---------------------------------------------------------------------------
// Prep: (a) c2 + zero cnt; (b) interleave codebook into B-fragment streaming
// records, PRE-SCALED BY -2 so the MFMA accumulates -2*dot directly and the
// accumulator is seeded with c2 (score = acc, no per-score fmaf).
// Record = 4KB per (stage, 16-cw tile): segments at byte 0/1024/2048/3072
// ([h0h][h1h][h0l][h1l]), each segment 64 lanes x 16B -> imm-offset friendly.
// ---------------------------------------------------------------------------
__global__ void rvq_prep(const float* __restrict__ cb,
                         unsigned short* __restrict__ cbi,
                         float* __restrict__ c2, unsigned* __restrict__ cnt) {
    int i = blockIdx.x * blockDim.x + threadIdx.x;   // 0..32767
    if (i < S * K) {   // c2 + cnt zero
        const float* row = cb + (size_t)i * D;
        float a0 = 0.f, a1 = 0.f, a2 = 0.f, a3 = 0.f;
#pragma unroll
        for (int d = 0; d < D; d += 4) {
            a0 = fmaf(row[d+0], row[d+0], a0);
            a1 = fmaf(row[d+1], row[d+1], a1);
            a2 = fmaf(row[d+2], row[d+2], a2);
            a3 = fmaf(row[d+3], row[d+3], a3);
        }
        c2[i] = (a0 + a1) + (a2 + a3);
        cnt[i] = 0u;
    }
    // interleave: i = s*4096 + tau*64 + l
    int s  = i >> 12;
    int tau = (i >> 6) & 63;
    int l  = i & 63;
    int m  = l & 15, qq = l >> 4;
    const float* row = cb + (size_t)(s * K + tau * 16 + m) * D;
    short8 h0h, h0l, h1h, h1l;
#pragma unroll
    for (int e = 0; e < 8; ++e) {
        float x = -2.0f * row[qq * 8 + e];
        unsigned short h = f2bf(x);
        h0h[e] = (short)h; h0l[e] = (short)f2bf(x - bf2f(h));
        float y = -2.0f * row[32 + qq * 8 + e];
        unsigned short g = f2bf(y);
        h1h[e] = (short)g; h1l[e] = (short)f2bf(y - bf2f(g));
    }
    unsigned short* rec = cbi + (size_t)(s * 64 + tau) * 2048 + l * 8;
    *(short8*)(rec +    0) = h0h;
    *(short8*)(rec +  512) = h1h;
    *(short8*)(rec + 1024) = h0l;
    *(short8*)(rec + 1536) = h1l;
}

// ---------------------------------------------------------------------------
// Main (R10): dual row-set waves + saddr diet + LDS residual spill.
// R9 post-mortem: L2 BW exonerated (8x traffic cut, flat); L2 latency
// exonerated (R6 vs R7 prefetch-depth null); VALU count small effect.
// Arithmetic: MFMA pipe cost = 12.6M x 19.4cyc/SIMD = ~100us -> MfmaUtil
// ~24% at 400us matches measurement; wall is ~2.5x the overlap floor from
// WITHIN-WAVE serialization (R7: single 6-long dependent MFMA chain/tile).
// Here: 2048 waves x 32 vectors; per tile 12 MFMA as FOUR independent
// 3-chains (4-way matrix ILP) sharing one 5-load tile stream (loads/MFMA
// halved vs R7). Register fit via LDS residual spill (rsp[32][65], 8.3KB):
// residuals are dead during the scan; frags rebuilt from LDS per stage;
// rescue reads LDS broadcast (replaces shfl); update/loss/epilogue RMW LDS.
// Single-wave blocks -> no barriers.
//
// launch_bounds EMPIRICAL RULE (R0-R4): VGPR cap = 256/arg2 on this
// toolchain. arg2 MUST stay 2 (cap 128). (x,4) capped at 64 -> spill, twice.
// ---------------------------------------------------------------------------
__global__ __launch_bounds__(64, 2)
void rvq_main(const float* __restrict__ z, const float* __restrict__ cbf,
              const unsigned short* __restrict__ cbi,
              const float* __restrict__ c2, float* __restrict__ zq,
              float* __restrict__ lossp, unsigned* __restrict__ cnt) {
    const int lane = threadIdx.x;
    const int m    = lane & 15;
    const int q    = lane >> 4;
    const int wid  = blockIdx.x;
    const int vbase = wid * 32;
    const int b    = vbase >> 12;
    const int ta   = (vbase & 4095) + m;    // set-a t (rows 0..15)
    const int tb   = ta + 16;               // set-b t (rows 16..31)
    const size_t zrow = ((size_t)(b * 64)) << 12;
    const int lo16 = lane * 16;     // per-lane byte offset into a segment
    const int lom  = m * 4;         // per-lane byte offset into c2 tile

    __shared__ float rsp[32][65];   // residual spill, +1 pad (8.3 KB)

    // ---- init: residuals <- z ----
#pragma unroll
    for (int i = 0; i < 8; ++i) {
        rsp[m][q*8+i]         = z[zrow + ((size_t)(q*8+i)    << 12) + ta];
        rsp[m][32+q*8+i]      = z[zrow + ((size_t)(32+q*8+i) << 12) + ta];
        rsp[16+m][q*8+i]      = z[zrow + ((size_t)(q*8+i)    << 12) + tb];
        rsp[16+m][32+q*8+i]   = z[zrow + ((size_t)(32+q*8+i) << 12) + tb];
    }

// load one 4KB tile record + its c2 scalar; advance uniform bases (SALU)
#define LOADB(i) {                                                           \
        B##i##0 = *(const short8*)(tp + lo16);                               \
        B##i##1 = *(const short8*)(tp + lo16 + 1024);                        \
        B##i##2 = *(const short8*)(tp + lo16 + 2048);                        \
        B##i##3 = *(const short8*)(tp + lo16 + 3072);                        \
        cc##i   = *(const float*)(cp + lom);                                 \
        tp += 4096; cp += 64;                                                \
    }

#define MF(A,B,C) __builtin_amdgcn_mfma_f32_16x16x32_bf16(A,B,C,0,0,0)

// 12 MFMA as 4 independent 3-chains (2 per row-set: dims 0-31 / 32-63)
#define COMPUTE(i, tt) {                                                     \
        float4v p0 = {cc##i, cc##i, cc##i, cc##i};                           \
        float4v p1 = {0.f, 0.f, 0.f, 0.f};                                   \
        float4v r0 = {cc##i, cc##i, cc##i, cc##i};                           \
        float4v r1 = {0.f, 0.f, 0.f, 0.f};                                   \
        __builtin_amdgcn_s_setprio(1);                                       \
        p0 = MF(xa0h, B##i##0, p0); r0 = MF(xb0h, B##i##0, r0);              \
        p1 = MF(xa1h, B##i##1, p1); r1 = MF(xb1h, B##i##1, r1);              \
        p0 = MF(xa0l, B##i##0, p0); r0 = MF(xb0l, B##i##0, r0);              \
        p1 = MF(xa1l, B##i##1, p1); r1 = MF(xb1l, B##i##1, r1);              \
        p0 = MF(xa0h, B##i##2, p0); r0 = MF(xb0h, B##i##2, r0);              \
        p1 = MF(xa1h, B##i##3, p1); r1 = MF(xb1h, B##i##3, r1);              \
        __builtin_amdgcn_s_setprio(0);                                       \
        const int ncol = (tt) * 16 + m;                                      \
        _Pragma("unroll")                                                    \
        for (int j = 0; j < 4; ++j) {                                        \
            float sa = p0[j] + p1[j];                                        \
            b2a[j] = __builtin_amdgcn_fmed3f(sa, b1a[j], b2a[j]);            \
            k1a[j] = (sa < b1a[j]) ? ncol : k1a[j];                          \
            b1a[j] = fminf(sa, b1a[j]);                                      \
            float sb = r0[j] + r1[j];                                        \
            b2b[j] = __builtin_amdgcn_fmed3f(sb, b1b[j], b2b[j]);            \
            k1b[j] = (sb < b1b[j]) ? ncol : k1b[j];                          \
            b1b[j] = fminf(sb, b1b[j]);                                      \
        }                                                                    \
    }

#pragma unroll 1
    for (int s = 0; s < S; ++s) {
        // ---- rebuild bf16 hi/lo A-fragments from LDS residuals ----
        short8 xa0h, xa0l, xa1h, xa1l, xb0h, xb0l, xb1h, xb1l;
#pragma unroll
        for (int i = 0; i < 8; ++i) {
            unsigned short h; float v;
            v = rsp[m][q*8+i];        h = f2bf(v); xa0h[i] = (short)h; xa0l[i] = (short)f2bf(v - bf2f(h));
            v = rsp[m][32+q*8+i];     h = f2bf(v); xa1h[i] = (short)h; xa1l[i] = (short)f2bf(v - bf2f(h));
            v = rsp[16+m][q*8+i];     h = f2bf(v); xb0h[i] = (short)h; xb0l[i] = (short)f2bf(v - bf2f(h));
            v = rsp[16+m][32+q*8+i];  h = f2bf(v); xb1h[i] = (short)h; xb1l[i] = (short)f2bf(v - bf2f(h));
        }

        float b1a[4], b2a[4], b1b[4], b2b[4];
        int   k1a[4], k1b[4];
#pragma unroll
        for (int j = 0; j < 4; ++j) {
            b1a[j] = 3.4e38f; b2a[j] = 3.4e38f; k1a[j] = 0;
            b1b[j] = 3.4e38f; b2b[j] = 3.4e38f; k1b[j] = 0;
        }

        const float* c2s = c2 + s * K;
        const char*  tp  = (const char*)(cbi + (size_t)s * 131072); // uniform
        const char*  cp  = (const char*)c2s;                        // uniform

        short8 B00, B01, B02, B03, B10, B11, B12, B13;  // two banks
        float  cc0, cc1;

        LOADB(0) LOADB(1)

#pragma unroll 1
        for (int it = 0; it < 31; ++it) {
            const int tau = it * 2;
            COMPUTE(0, tau + 0) LOADB(0)     // reload tile tau+2
            COMPUTE(1, tau + 1) LOADB(1)     // reload tile tau+3
        }
        COMPUTE(0, 62) COMPUTE(1, 63)

        // ---- reduce across the 16 col-lanes (k-tie: lowest k) ----
#pragma unroll
        for (int off = 1; off < 16; off <<= 1) {
#pragma unroll
            for (int j = 0; j < 4; ++j) {
                float o1 = __shfl_xor(b1a[j], off); int ok = __shfl_xor(k1a[j], off);
                float o2 = __shfl_xor(b2a[j], off);
                float n2 = fminf(fminf(b2a[j], o2), fmaxf(b1a[j], o1));
                bool tk = (o1 < b1a[j]) || (o1 == b1a[j] && ok < k1a[j]);
                k1a[j] = tk ? ok : k1a[j]; b1a[j] = fminf(b1a[j], o1); b2a[j] = n2;
                o1 = __shfl_xor(b1b[j], off); ok = __shfl_xor(k1b[j], off);
                o2 = __shfl_xor(b2b[j], off);
                n2 = fminf(fminf(b2b[j], o2), fmaxf(b1b[j], o1));
                tk = (o1 < b1b[j]) || (o1 == b1b[j] && ok < k1b[j]);
                k1b[j] = tk ? ok : k1b[j]; b1b[j] = fminf(b1b[j], o1); b2b[j] = n2;
            }
        }

        // ---- δ-rescue: exact fp32 rescan of ambiguous rows (rare) ----
        // residual of row ROW+mrow read from LDS (broadcast, replaces shfl)
        const float* cr0 = cbf + (size_t)s * 65536;
#define RESCUE(b1X, b2X, k1X, ROW)                                            \
        for (int j = 0; j < 4; ++j) {                                         \
            unsigned long long mask = __ballot(b2X[j] - b1X[j] < DELTA);      \
            while (mask) {                                                    \
                int lq = (int)(__builtin_ctzll(mask)) >> 4;                   \
                mask &= ~(0xFFFFULL << (lq * 16));                            \
                int mrow = lq * 4 + j;                                        \
                float bd = 3.4e38f; int bk = 0;                               \
                for (int cc = 0; cc < 16; ++cc) {                             \
                    int n = cc * 64 + lane;                                   \
                    const float* crow = cr0 + (size_t)n * 64;                 \
                    float dot = 0.f;                                          \
                    for (int d = 0; d < 64; ++d)                              \
                        dot = fmaf(rsp[(ROW) + mrow][d], crow[d], dot);       \
                    float sc = c2s[n] - 2.f * dot;                            \
                    if (sc < bd) { bd = sc; bk = n; }                         \
                }                                                             \
                for (int off = 1; off < 64; off <<= 1) {                      \
                    float ob = __shfl_xor(bd, off); int ok = __shfl_xor(bk, off); \
                    bool tk = (ob < bd) || (ob == bd && ok < bk);             \
                    bk = tk ? ok : bk; bd = fminf(bd, ob);                    \
                }                                                             \
                if (q == lq) k1X[j] = bk;                                     \
            }                                                                 \
        }
        RESCUE(b1a, b2a, k1a, 0)
        RESCUE(b1b, b2b, k1b, 16)
#undef RESCUE

        // ---- transpose winners to per-lane rows (row = m), convergent ----
        int mm = m & 3, src = (m >> 2) * 16;
        int wa0 = __shfl(k1a[0], src), wa1 = __shfl(k1a[1], src);
        int wa2 = __shfl(k1a[2], src), wa3 = __shfl(k1a[3], src);
        int bka = (mm == 0) ? wa0 : (mm == 1) ? wa1 : (mm == 2) ? wa2 : wa3;
        int wb0 = __shfl(k1b[0], src), wb1 = __shfl(k1b[1], src);
        int wb2 = __shfl(k1b[2], src), wb3 = __shfl(k1b[3], src);
        int bkb = (mm == 0) ? wb0 : (mm == 1) ? wb1 : (mm == 2) ? wb2 : wb3;

        // ---- fp32 residual update in LDS + loss ----
        const float* qa = cbf + (size_t)s * 65536 + (size_t)bka * 64;
        const float* qb = cbf + (size_t)s * 65536 + (size_t)bkb * 64;
        float ls = 0.f;
#pragma unroll
        for (int i = 0; i < 8; ++i) {
            float na = rsp[m][q*8+i]        - qa[q*8+i];
            float nb = rsp[m][32+q*8+i]     - qa[32+q*8+i];
            float nc = rsp[16+m][q*8+i]     - qb[q*8+i];
            float nd = rsp[16+m][32+q*8+i]  - qb[32+q*8+i];
            rsp[m][q*8+i] = na;        rsp[m][32+q*8+i] = nb;
            rsp[16+m][q*8+i] = nc;     rsp[16+m][32+q*8+i] = nd;
            ls = fmaf(na, na, ls); ls = fmaf(nb, nb, ls);
            ls = fmaf(nc, nc, ls); ls = fmaf(nd, nd, ls);
        }
#pragma unroll
        for (int off = 1; off < 64; off <<= 1) ls += __shfl_xor(ls, off);
        if (lane == 0) lossp[s * NW + wid] = ls;

        // ---- histogram: per-vector winners (dup across q) ----
        if (q == 0) {
            atomicAdd(&cnt[s * K + bka], 1u);   // vector vbase+m
            atomicAdd(&cnt[s * K + bkb], 1u);   // vector vbase+16+m
        }
    }
#undef LOADB
#undef COMPUTE
#undef MF

    // ---- epilogue: zq = z - r_final ----
#pragma unroll
    for (int i = 0; i < 8; ++i) {
        size_t a0 = zrow + ((size_t)(q*8+i)    << 12) + ta;
        size_t a1 = zrow + ((size_t)(32+q*8+i) << 12) + ta;
        zq[a0] = z[a0] - rsp[m][q*8+i];
        zq[a1] = z[a1] - rsp[m][32+q*8+i];
        size_t a2 = zrow + ((size_t)(q*8+i)    << 12) + tb;
        size_t a3 = zrow + ((size_t)(32+q*8+i) << 12) + tb;
        zq[a2] = z[a2] - rsp[16+m][q*8+i];
        zq[a3] = z[a3] - rsp[16+m][32+q*8+i];
    }
}

// ---------------------------------------------------------------------------
// Finalize: losses (mean of summed wave partials) + perplexities
// ---------------------------------------------------------------------------
__global__ void rvq_finalize(const float* __restrict__ lossp,
                             const unsigned* __restrict__ cnt,
                             float* __restrict__ out_loss,
                             float* __restrict__ out_perp) {
    const int s   = blockIdx.x;
    const int tid = threadIdx.x;
    float ent = 0.f, lsum = 0.f;
    for (int i = tid; i < K; i += 256) {
        float p = (float)cnt[s * K + i] * (1.0f / 65536.0f);
        ent += p * logf(p + EPSQ);
    }
    for (int i = tid; i < NW; i += 256) lsum += lossp[s * NW + i];
    __shared__ float redE[4], redL[4];
#pragma unroll
    for (int off = 32; off > 0; off >>= 1) {
        ent  += __shfl_down(ent, off);
        lsum += __shfl_down(lsum, off);
    }
    if ((tid & 63) == 0) { redE[tid >> 6] = ent; redL[tid >> 6] = lsum; }
    __syncthreads();
    if (tid == 0) {
        float te = redE[0] + redE[1] + redE[2] + redE[3];
        float tl = redL[0] + redL[1] + redL[2] + redL[3];
        out_perp[s] = expf(-te);
        out_loss[s] = tl * (1.0f / NELEM);
    }
}

// ---------------------------------------------------------------------------
extern "C" void kernel_launch(void* const* d_in, const int* in_sizes, int n_in,
                              void* d_out, int out_size, void* d_ws, size_t ws_size,
                              hipStream_t stream) {
    const float* z  = (const float*)d_in[0];
    const float* cb = (const float*)d_in[1];

    float* zq       = (float*)d_out;
    float* out_loss = zq + 4194304;
    float* out_perp = out_loss + 8;

    // ws: cbi 2 MB | c2 32 KB | cnt 32 KB | lossp 64 KB
    char* ws = (char*)d_ws;
    unsigned short* cbi = (unsigned short*)(ws);
    float*    c2    = (float*)(ws + 2097152);
    unsigned* cnt   = (unsigned*)(ws + 2129920);
    float*    lossp = (float*)(ws + 2162688);

    hipLaunchKernelGGL(rvq_prep,     dim3(128),  dim3(256), 0, stream, cb, cbi, c2, cnt);
    hipLaunchKernelGGL(rvq_main,     dim3(NW),   dim3(64),  0, stream, z, cb, cbi, c2, zq, lossp, cnt);
    hipLaunchKernelGGL(rvq_finalize, dim3(S),    dim3(256), 0, stream, lossp, cnt, out_loss, out_perp);
}